// Round 2
// baseline (600.188 us; speedup 1.0000x reference)
//
#include <hip/hip_runtime.h>
#include <stdint.h>

// Problem constants (reference: BATCH=65536, MAX_LENGTH=64)
#define NBATCH 65536
#define LSEQ   64

// d_ws float layout (transposed weights, fp32)
#define WS_W2T   0      // [64 j][32 i]  W2T[j*32+i] = W2[i][j]
#define WS_WDT   2048   // [32 i][10 d]  WdT[i*10+d] = Wd[d][i]
#define WS_WCT   2368   // [32 i][2 c]
#define WS_B2    2432   // [32]
#define WS_BD    2464   // [10]
#define WS_BC    2474   // [2]

__global__ void prep_kernel(const float* __restrict__ W2,
                            const float* __restrict__ Wd,
                            const float* __restrict__ Wc,
                            const float* __restrict__ b2,
                            const float* __restrict__ bd,
                            const float* __restrict__ bc,
                            float* __restrict__ ws){
    int t = threadIdx.x;
    for (int e = t; e < 2048; e += 256){ int j = e >> 5, i = e & 31; ws[WS_W2T + e] = W2[i*64 + j]; }
    for (int e = t; e < 320;  e += 256){ int i = e / 10, d = e - i*10; ws[WS_WDT + e] = Wd[d*32 + i]; }
    for (int e = t; e < 64;   e += 256){ int i = e >> 1, c = e & 1;   ws[WS_WCT + e] = Wc[c*32 + i]; }
    if (t < 32) ws[WS_B2 + t] = b2[t];
    if (t < 10) ws[WS_BD + t] = bd[t];
    if (t < 2)  ws[WS_BC + t] = bc[t];
}

__global__ __launch_bounds__(256)
void mlp_seq_kernel(const int* __restrict__ a, const int* __restrict__ b,
                    const float* __restrict__ Ea, const float* __restrict__ Eb,
                    const float* __restrict__ W1, const float* __restrict__ b1,
                    const float* __restrict__ ws, float* __restrict__ out){
    // LDS: layer-1 contribution table over the 100 (a,b) digit pairs.
    // Pab[p][j] = b1[j] + W1[j][17] + Ea[p/10]·W1[j][0:8] + Eb[p%10]·W1[j][8:16]
    // h1[j] = relu(Pab[p][j] + carry0 * (W1[j][16] - W1[j][17]))   (carry sums to 1)
    __shared__ float Pab[100 * 65];   // stride 65 spreads banks
    __shared__ float Dc[64];

    const int tid = threadIdx.x;
    for (int e = tid; e < 6400; e += 256){
        int p = e >> 6, j = e & 63;
        int da = p / 10, db = p - da * 10;
        float acc = b1[j] + W1[j*18 + 17];
        #pragma unroll
        for (int k = 0; k < 8; k++){
            acc = fmaf(Ea[da*8 + k], W1[j*18 + k],     acc);
            acc = fmaf(Eb[db*8 + k], W1[j*18 + 8 + k], acc);
        }
        Pab[p*65 + j] = acc;
    }
    if (tid < 64) Dc[tid] = W1[tid*18 + 16] - W1[tid*18 + 17];
    __syncthreads();

    const float* __restrict__ W2T = ws + WS_W2T;
    const float* __restrict__ WdT = ws + WS_WDT;
    const float* __restrict__ WcT = ws + WS_WCT;
    const float* __restrict__ B2  = ws + WS_B2;
    const float* __restrict__ BD  = ws + WS_BD;
    const float* __restrict__ BC  = ws + WS_BC;

    const int t = blockIdx.x * 256 + tid;           // sample index
    const int4* ap = (const int4*)(a + (size_t)t * LSEQ);
    const int4* bp = (const int4*)(b + (size_t)t * LSEQ);

    float carry0 = 1.0f;
    const unsigned long long obase = (unsigned long long)t * LSEQ;
    float2* __restrict__ o2 = (float2*)out;
    const unsigned long long cbase = (unsigned long long)NBATCH * LSEQ * 10ull / 2ull;

    unsigned int pk = 0;
    for (int s = 0; s < LSEQ; s++){
        if ((s & 3) == 0){
            int g = s >> 2;
            int4 av = ap[g], bv = bp[g];
            pk = (unsigned)(av.x*10 + bv.x)        | ((unsigned)(av.y*10 + bv.y) << 8)
               | ((unsigned)(av.z*10 + bv.z) << 16)| ((unsigned)(av.w*10 + bv.w) << 24);
        }
        const int idx = (pk >> ((s & 3) * 8)) & 255;
        const float* prow = Pab + idx * 65;

        float h2[32];
        #pragma unroll
        for (int i = 0; i < 32; i++) h2[i] = B2[i];

        #pragma unroll 4
        for (int j = 0; j < 64; j++){
            float h1 = fmaxf(fmaf(carry0, Dc[j], prow[j]), 0.0f);
            const float* wr = W2T + j * 32;           // wave-uniform -> scalar loads
            #pragma unroll
            for (int i = 0; i < 32; i++) h2[i] = fmaf(h1, wr[i], h2[i]);
        }

        float dg[10];
        #pragma unroll
        for (int d = 0; d < 10; d++) dg[d] = BD[d];
        float c0 = BC[0], c1 = BC[1];
        #pragma unroll
        for (int i = 0; i < 32; i++){
            float h = fmaxf(h2[i], 0.0f);
            const float* wr = WdT + i * 10;
            #pragma unroll
            for (int d = 0; d < 10; d++) dg[d] = fmaf(h, wr[d], dg[d]);
            c0 = fmaf(h, WcT[i*2 + 0], c0);
            c1 = fmaf(h, WcT[i*2 + 1], c1);
        }

        // Outputs: digit logits [B,L,10] then carry logits [B,L,2], fp32.
        const unsigned long long ss = obase + (unsigned)s;
        const unsigned long long d5 = ss * 5ull;     // float2 units
        #pragma unroll
        for (int q = 0; q < 5; q++)
            o2[d5 + q] = make_float2(dg[2*q], dg[2*q + 1]);
        o2[cbase + ss] = make_float2(c0, c1);

        // next carry_in[0] = softmax(c)[0] = sigmoid(c0 - c1)
        carry0 = 1.0f / (1.0f + __expf(c1 - c0));
    }
}

extern "C" void kernel_launch(void* const* d_in, const int* in_sizes, int n_in,
                              void* d_out, int out_size, void* d_ws, size_t ws_size,
                              hipStream_t stream) {
    const int*   a  = (const int*)d_in[0];
    const int*   b  = (const int*)d_in[1];
    const float* Ea = (const float*)d_in[2];
    const float* Eb = (const float*)d_in[3];
    const float* W1 = (const float*)d_in[4];
    const float* b1 = (const float*)d_in[5];
    const float* W2 = (const float*)d_in[6];
    const float* b2 = (const float*)d_in[7];
    const float* Wd = (const float*)d_in[8];
    const float* bd = (const float*)d_in[9];
    const float* Wc = (const float*)d_in[10];
    const float* bc = (const float*)d_in[11];

    float* ws = (float*)d_ws;
    prep_kernel<<<1, 256, 0, stream>>>(W2, Wd, Wc, b2, bd, bc, ws);
    mlp_seq_kernel<<<NBATCH / 256, 256, 0, stream>>>(a, b, Ea, Eb, W1, b1, ws,
                                                     (float*)d_out);
}

// Round 3
// 313.444 us; speedup vs baseline: 1.9148x; 1.9148x over previous
//
#include <hip/hip_runtime.h>
#include <hip/hip_bf16.h>
#include <stdint.h>

#define NBATCH 65536
#define LSEQ   64

typedef __attribute__((ext_vector_type(8))) short short8;
typedef __attribute__((ext_vector_type(4))) float f32x4;
typedef __attribute__((ext_vector_type(4))) int   i32x4;

static __device__ __forceinline__ int pk_bf16(float x, float y){
    union { __hip_bfloat162 h; int i; } u;
    u.h = __float22bfloat162_rn(float2{x, y});
    return u.i;
}

// 1 wave = 16 samples. Layer1 folded into LDS table + carry FMA (carry softmax
// sums to 1: in·W1c = W1c1 + carry0·(W1c0-W1c1)). Layers 2+3 on MFMA
// 16x16x32 bf16, fp32 accumulate. Block = 4 waves = 64 samples.
__global__ __launch_bounds__(256, 4)
void mlp_mfma_kernel(const int* __restrict__ a, const int* __restrict__ b,
                     const float* __restrict__ Ea, const float* __restrict__ Eb,
                     const float* __restrict__ W1, const float* __restrict__ b1,
                     const float* __restrict__ W2, const float* __restrict__ b2,
                     const float* __restrict__ Wd, const float* __restrict__ bd,
                     const float* __restrict__ Wc, const float* __restrict__ bc,
                     float* __restrict__ out)
{
    __shared__ float Pab[100*68];          // stride 68: 16B-aligned rows, idx spreads banks
    __shared__ unsigned char pkL[64*64];   // [step][local sample] packed digit pair
    __shared__ float scr[4][32*17];        // per-wave h2 re-partition scratch

    const int tid = threadIdx.x;
    const int wv  = tid >> 6;
    const int l   = tid & 63;
    const int q   = l >> 4;        // lane quad: k-group for A/B frags, row-group for C
    const int n   = l & 15;        // sample (col) within wave / row within A

    const int sBase = blockIdx.x * 64;

    // ---- stage digits: coalesced int4 loads -> packed bytes [s][n] ----
    {
        const i32x4* ap = (const i32x4*)(a + (size_t)sBase * LSEQ);
        const i32x4* bp = (const i32x4*)(b + (size_t)sBase * LSEQ);
        #pragma unroll
        for (int k = 0; k < 4; k++){
            int v = tid + k*256;                 // int4 index within block's 64x64
            i32x4 av = ap[v], bv = bp[v];
            int ns = v >> 4, s0 = (v & 15) << 2;
            pkL[(s0+0)*64 + ns] = (unsigned char)(av[0]*10 + bv[0]);
            pkL[(s0+1)*64 + ns] = (unsigned char)(av[1]*10 + bv[1]);
            pkL[(s0+2)*64 + ns] = (unsigned char)(av[2]*10 + bv[2]);
            pkL[(s0+3)*64 + ns] = (unsigned char)(av[3]*10 + bv[3]);
        }
    }

    // ---- layer-1 table: Pab[p][j] = b1[j] + W1[j][17] + Ea[p/10]·W1[j][0:8] + Eb[p%10]·W1[j][8:16]
    for (int e = tid; e < 6400; e += 256){
        int p = e >> 6, j = e & 63;
        int da = p / 10, db = p - da*10;
        float acc = b1[j] + W1[j*18 + 17];
        #pragma unroll
        for (int k2 = 0; k2 < 8; k2++){
            acc = fmaf(Ea[da*8 + k2], W1[j*18 + k2],     acc);
            acc = fmaf(Eb[db*8 + k2], W1[j*18 + 8 + k2], acc);
        }
        Pab[p*68 + j] = acc;
    }

    // ---- per-lane constants (registers) ----
    float DcR[16];                               // Dc[j] slice for this lane's k-positions
    #pragma unroll
    for (int kc = 0; kc < 2; kc++)
        #pragma unroll
        for (int jj = 0; jj < 8; jj++){
            int j = kc*32 + q*8 + jj;
            DcR[kc*8+jj] = W1[j*18 + 16] - W1[j*18 + 17];
        }

    // W2 A-frags: A[m = n][k = q*8+jj], m-tile mt, k-chunk kc
    short8 w2f[2][2];
    #pragma unroll
    for (int mt = 0; mt < 2; mt++)
        #pragma unroll
        for (int kc = 0; kc < 2; kc++){
            union { short8 f; i32x4 d; } u;
            int m = mt*16 + n;
            #pragma unroll
            for (int jj = 0; jj < 8; jj += 2){
                int k = kc*32 + q*8 + jj;
                u.d[jj>>1] = pk_bf16(W2[m*64 + k], W2[m*64 + k + 1]);
            }
            w2f[mt][kc] = u.f;
        }

    // W3 A-frag: rows 0-9 = Wd, 10-11 = Wc, 12-15 = 0
    short8 w3f;
    {
        union { short8 f; i32x4 d; } u;
        #pragma unroll
        for (int jj = 0; jj < 8; jj += 2){
            int k = q*8 + jj;
            float x0 = 0.f, x1 = 0.f;
            if (n < 10)      { x0 = Wd[n*32+k];      x1 = Wd[n*32+k+1]; }
            else if (n < 12) { x0 = Wc[(n-10)*32+k]; x1 = Wc[(n-10)*32+k+1]; }
            u.d[jj>>1] = pk_bf16(x0, x1);
        }
        w3f = u.f;
    }

    float b2r[8], b3r[4];                        // biases at this lane's C rows
    #pragma unroll
    for (int mt = 0; mt < 2; mt++)
        #pragma unroll
        for (int r = 0; r < 4; r++) b2r[mt*4+r] = b2[mt*16 + q*4 + r];
    #pragma unroll
    for (int r = 0; r < 4; r++){
        int m = q*4 + r;
        b3r[r] = (m < 10) ? bd[m] : (m < 12 ? bc[m-10] : 0.f);
    }

    __syncthreads();

    const int tn = sBase + wv*16 + n;            // this lane's sample
    float carry = 1.0f;
    float* scrw = scr[wv];
    float2* __restrict__ o2 = (float2*)out;
    const unsigned long long cbase2 = (unsigned long long)NBATCH * LSEQ * 5ull; // carry sect, float2 units
    const unsigned long long obase  = (unsigned long long)tn * LSEQ;

    for (int s = 0; s < LSEQ; s++){
        const int idx = pkL[s*64 + wv*16 + n];
        const float* prow = Pab + idx*68 + q*8;

        // H1 B-frags: B[k = q*8+jj][n], k-chunks kc
        short8 h1f[2];
        #pragma unroll
        for (int kc = 0; kc < 2; kc++){
            f32x4 p0 = *(const f32x4*)(prow + kc*32);
            f32x4 p1 = *(const f32x4*)(prow + kc*32 + 4);
            float h[8];
            #pragma unroll
            for (int jj = 0; jj < 4; jj++){
                h[jj]   = fmaxf(fmaf(carry, DcR[kc*8+jj],   p0[jj]), 0.f);
                h[jj+4] = fmaxf(fmaf(carry, DcR[kc*8+jj+4], p1[jj]), 0.f);
            }
            union { short8 f; i32x4 d; } u;
            u.d[0] = pk_bf16(h[0], h[1]);
            u.d[1] = pk_bf16(h[2], h[3]);
            u.d[2] = pk_bf16(h[4], h[5]);
            u.d[3] = pk_bf16(h[6], h[7]);
            h1f[kc] = u.f;
        }

        // layer 2: h2[32 x 16] = W2 · H1  (bias in acc init)
        f32x4 acc2a = { b2r[0], b2r[1], b2r[2], b2r[3] };
        f32x4 acc2b = { b2r[4], b2r[5], b2r[6], b2r[7] };
        acc2a = __builtin_amdgcn_mfma_f32_16x16x32_bf16(w2f[0][0], h1f[0], acc2a, 0,0,0);
        acc2a = __builtin_amdgcn_mfma_f32_16x16x32_bf16(w2f[0][1], h1f[1], acc2a, 0,0,0);
        acc2b = __builtin_amdgcn_mfma_f32_16x16x32_bf16(w2f[1][0], h1f[0], acc2b, 0,0,0);
        acc2b = __builtin_amdgcn_mfma_f32_16x16x32_bf16(w2f[1][1], h1f[1], acc2b, 0,0,0);

        // re-partition h2: C layout (rows q*4+r) -> B layout (rows q*8..q*8+8), relu fused
        #pragma unroll
        for (int r = 0; r < 4; r++){
            scrw[(q*4 + r)*17 + n]      = acc2a[r];
            scrw[(16 + q*4 + r)*17 + n] = acc2b[r];
        }
        __builtin_amdgcn_wave_barrier();        // keep reads after writes (same-wave DS is in-order)
        short8 h2f;
        {
            float h[8];
            #pragma unroll
            for (int jj = 0; jj < 8; jj++)
                h[jj] = fmaxf(scrw[(q*8 + jj)*17 + n], 0.f);
            __builtin_amdgcn_wave_barrier();    // keep next iter's writes after these reads
            union { short8 f; i32x4 d; } u;
            u.d[0] = pk_bf16(h[0], h[1]);
            u.d[1] = pk_bf16(h[2], h[3]);
            u.d[2] = pk_bf16(h[4], h[5]);
            u.d[3] = pk_bf16(h[6], h[7]);
            h2f = u.f;
        }

        // layer 3: logits[16 x 16] (rows 0-9 digit, 10-11 carry, 12-15 pad)
        f32x4 acc3 = { b3r[0], b3r[1], b3r[2], b3r[3] };
        acc3 = __builtin_amdgcn_mfma_f32_16x16x32_bf16(w3f, h2f, acc3, 0,0,0);

        // carry0 = sigmoid(c0 - c1); c0,c1 live in lane 32+n regs 2,3
        float diff = acc3[2] - acc3[3];
        int dv = __builtin_amdgcn_ds_bpermute((32+n) << 2, __float_as_int(diff));
        carry = 1.0f / (1.0f + __expf(-__int_as_float(dv)));

        // stores: lane q holds logit rows q*4..q*4+4 for sample n
        const unsigned long long ss = obase + (unsigned)s;
        const unsigned long long d2 = ss * 5ull;          // float2 units into digit section
        if (q == 0){
            o2[d2+0] = float2{acc3[0], acc3[1]};
            o2[d2+1] = float2{acc3[2], acc3[3]};
        } else if (q == 1){
            o2[d2+2] = float2{acc3[0], acc3[1]};
            o2[d2+3] = float2{acc3[2], acc3[3]};
        } else if (q == 2){
            o2[d2+4] = float2{acc3[0], acc3[1]};
            o2[cbase2 + ss] = float2{acc3[2], acc3[3]};
        }
    }
}

extern "C" void kernel_launch(void* const* d_in, const int* in_sizes, int n_in,
                              void* d_out, int out_size, void* d_ws, size_t ws_size,
                              hipStream_t stream) {
    const int*   a  = (const int*)d_in[0];
    const int*   b  = (const int*)d_in[1];
    const float* Ea = (const float*)d_in[2];
    const float* Eb = (const float*)d_in[3];
    const float* W1 = (const float*)d_in[4];
    const float* b1 = (const float*)d_in[5];
    const float* W2 = (const float*)d_in[6];
    const float* b2 = (const float*)d_in[7];
    const float* Wd = (const float*)d_in[8];
    const float* bd = (const float*)d_in[9];
    const float* Wc = (const float*)d_in[10];
    const float* bc = (const float*)d_in[11];

    mlp_mfma_kernel<<<NBATCH / 64, 256, 0, stream>>>(a, b, Ea, Eb, W1, b1,
                                                     W2, b2, Wd, bd, Wc, bc,
                                                     (float*)d_out);
}